// Round 17
// baseline (527.858 us; speedup 1.0000x reference)
//
#include <hip/hip_runtime.h>

#define DI __device__ __forceinline__

typedef float f32x4 __attribute__((ext_vector_type(4)));
typedef float f4    __attribute__((ext_vector_type(4)));
typedef _Float16 h8 __attribute__((ext_vector_type(8)));
typedef _Float16 h4 __attribute__((ext_vector_type(4)));

// sizes
#define SEQL 512
#define BATCH 256
#define INF 300
#define HID 256
#define N2 512   // 2*HID
#define KP 320   // INF padded to multiple of 64

// pre3 layout: element (t, j, b) at byte t*262144 + (j>>4)*8192 + b*32 + (j&15)*2

DI float ftanh(float x) {
    float e = __builtin_amdgcn_exp2f(x * 2.8853900817779268f);
    return fmaf(-2.0f, __builtin_amdgcn_rcpf(e + 1.0f), 1.0f);
}

// ---------------- prep: WcatT (xor-swizzled f16) + bcat ----------------
__global__ void prep_kernel(const float* __restrict__ W1x, const float* __restrict__ W2x,
                            const float* __restrict__ b1, const float* __restrict__ b2,
                            _Float16* __restrict__ WTs, float* __restrict__ bcat)
{
    int idx = blockIdx.x * 256 + threadIdx.x;
    if (idx < N2 * KP) {
        int j = idx / KP, z = idx - j * KP;
        int k = z ^ ((j & 7) << 3);
        float v = 0.f;
        if (k < INF) v = (j < HID) ? W1x[k * HID + j] : W2x[k * HID + (j - HID)];
        WTs[j * KP + z] = (_Float16)v;
    }
    if (idx < N2) bcat[idx] = (idx < HID) ? b1[idx] : b2[idx - HID];
}

// ---------------- GEMM (persistent-W): 256 blocks, 1/CU, 112KB dyn LDS ----------------
// Block owns (stripe of 16 m-tiles) x (j-quarter of 128 j). W-quarter (80KB) loaded ONCE
// via straight DMA (pre-swizzled source); K-loop reads W from LDS. x dbuf per m-tile.
// XCD map: all 4 jq of one stripe live on the same XCD -> x fetched from HBM once.
__global__ __launch_bounds__(512, 1) void gemm_persist(
    const float* __restrict__ x, const _Float16* __restrict__ WTs,
    const float* __restrict__ bcat, _Float16* __restrict__ pre3)
{
    extern __shared__ char smem[];
    char* Wp = smem;                       // 80KB: W rows [128 j][320 k], in-row xor-swizzle
    char* Ax0 = smem + 81920;              // 16KB x tile (xor-swizzled rows)
    char* Ax1 = smem + 81920 + 16384;      // 16KB x tile
    const int tid = threadIdx.x;
    const int w = tid >> 6, l = tid & 63;
    const int lj = l & 15, lg = l >> 4;
    const int bid = blockIdx.x;
    const int xcd = bid & 7;
    const int idx = bid >> 3;              // 0..31
    const int stripe = xcd * 8 + (idx & 7);// 0..63 (16 m-tiles each)
    const int jq = idx >> 3;               // 0..3
    const int j0b = jq * 128;
    const int wm2 = (w & 1) * 64, wj = (w >> 1) * 32;

    // ---- W prologue: 80KB straight DMA (10 rounds x 8KB), source pre-swizzled ----
#pragma unroll
    for (int q = 0; q < 10; ++q) {
        const _Float16* src = WTs + (size_t)j0b * KP + q * 4096 + (w * 64 + l) * 8;
        _Float16* dst = (_Float16*)(Wp + q * 8192 + w * 1024);  // wave-uniform base
        __builtin_amdgcn_global_load_lds(
            (const __attribute__((address_space(1))) void*)src,
            (__attribute__((address_space(3))) void*)dst, 16, 0, 0);
    }
    asm volatile("s_waitcnt vmcnt(0)" ::: "memory");
    __builtin_amdgcn_s_barrier();

    f4 bias4[2];
#pragma unroll
    for (int jt = 0; jt < 2; ++jt)
        bias4[jt] = *(const f4*)(bcat + j0b + wj + jt * 16 + lg * 4);

#define LOAD_X(M0, K0, XR)                                                            \
    do {                                                                              \
        _Pragma("unroll")                                                             \
        for (int c = 0; c < 4; ++c) {                                                 \
            int f = c * 512 + tid;                                                    \
            int mr = f >> 4, k4 = f & 15;                                             \
            if ((K0) + k4 * 4 + 3 < INF)                                              \
                XR[c] = *(const f4*)(x + ((M0) + mr) * INF + (K0) + k4 * 4);          \
            else                                                                      \
                XR[c] = f4{0.f, 0.f, 0.f, 0.f};                                       \
        }                                                                             \
    } while (0)

#define WRITE_X(XR, ADST)                                                             \
    do {                                                                              \
        _Pragma("unroll")                                                             \
        for (int c = 0; c < 4; ++c) {                                                 \
            int f = c * 512 + tid;                                                    \
            int mr = f >> 4, k4 = f & 15;                                             \
            unsigned bo = (unsigned)mr * 128 + (((unsigned)k4 * 8) ^ ((mr & 7) << 4)); \
            *(h4*)((ADST) + bo) = h4{(_Float16)XR[c][0], (_Float16)XR[c][1],          \
                                     (_Float16)XR[c][2], (_Float16)XR[c][3]};         \
        }                                                                             \
    } while (0)

#define GBARRIER()                                                                    \
    do {                                                                              \
        __builtin_amdgcn_sched_barrier(0);                                            \
        asm volatile("s_waitcnt vmcnt(0) lgkmcnt(0)" ::: "memory");                   \
        __builtin_amdgcn_s_barrier();                                                 \
        __builtin_amdgcn_sched_barrier(0);                                            \
    } while (0)

    char* prc = (char*)pre3;

    for (int mi = 0; mi < 16; ++mi) {
        const int bm = stripe * 16 + mi;
        const size_t m0 = (size_t)bm * 128;

        f32x4 acc[2][4];  // [jt][mt]
#pragma unroll
        for (int a = 0; a < 2; ++a)
#pragma unroll
            for (int b = 0; b < 4; ++b) acc[a][b] = f32x4{0.f, 0.f, 0.f, 0.f};

        char* Acur = Ax0;
        char* Anxt = Ax1;
        // stage s=0
        {
            f4 xr[4];
            LOAD_X(m0, 0, xr);
            asm volatile("s_waitcnt vmcnt(0)" ::: "memory");
            WRITE_X(xr, Acur);
            GBARRIER();
        }
        for (int s = 0; s < 5; ++s) {
            f4 xr[4];
            if (s < 4) LOAD_X(m0, (s + 1) * 64, xr);
#pragma unroll
            for (int kk = 0; kk < 2; ++kk) {
                h8 aw[2], bx[4];
#pragma unroll
                for (int jt = 0; jt < 2; ++jt) {
                    int jr = wj + jt * 16 + lj;
                    unsigned bo = (unsigned)jr * 640 + (unsigned)s * 128
                                + (((unsigned)(kk * 64 + lg * 16)) ^ ((jr & 7) << 4));
                    aw[jt] = *(const h8*)(Wp + bo);
                }
#pragma unroll
                for (int mt = 0; mt < 4; ++mt) {
                    int mr = wm2 + mt * 16 + lj;
                    unsigned bo = (unsigned)mr * 128 + (((unsigned)(kk * 64 + lg * 16)) ^ ((mr & 7) << 4));
                    bx[mt] = *(const h8*)(Acur + bo);
                }
#pragma unroll
                for (int jt = 0; jt < 2; ++jt)
#pragma unroll
                    for (int mt = 0; mt < 4; ++mt)
                        acc[jt][mt] = __builtin_amdgcn_mfma_f32_16x16x32_f16(aw[jt], bx[mt], acc[jt][mt], 0, 0, 0);
            }
            if (s < 4) {
                asm volatile("s_waitcnt vmcnt(0)" ::: "memory");
                WRITE_X(xr, Anxt);
            }
            GBARRIER();
            char* t0 = Acur; Acur = Anxt; Anxt = t0;
        }
        // epilogue for this m-tile: 8 coalesced 8B stores
#pragma unroll
        for (int jt = 0; jt < 2; ++jt) {
            int slab = (j0b + wj + jt * 16) >> 4;
#pragma unroll
            for (int mt = 0; mt < 4; ++mt) {
                int M = (int)m0 + wm2 + mt * 16;
                size_t byte = (size_t)(M >> 8) * 262144 + (size_t)slab * 8192
                            + (size_t)((M & 255) + lj) * 32 + (size_t)lg * 8;
                h4 o;
#pragma unroll
                for (int i = 0; i < 4; ++i)
                    o[i] = (_Float16)(acc[jt][mt][i] + bias4[jt][i]);
                *(h4*)(prc + byte) = o;
            }
        }
    }
#undef LOAD_X
#undef WRITE_X
#undef GBARRIER
}

// ---------------- GEMM fallback (R16-verified, static LDS) ----------------
__global__ __launch_bounds__(512, 2) void gemm_pre(
    const float* __restrict__ x, const _Float16* __restrict__ WTs,
    const float* __restrict__ bcat, _Float16* __restrict__ pre3)
{
    __shared__ _Float16 AbD[2][128 * 64];
    __shared__ _Float16 BbD[2][256 * 64];
    const int tid = threadIdx.x;
    const int w = tid >> 6, l = tid & 63;
    const int lj = l & 15, lg = l >> 4;
    const int bid = blockIdx.x;
    const int xcd = bid & 7;
    const int idx0 = bid >> 3;
    const int jn = idx0 & 1;
    const int bm = xcd * 128 + (idx0 >> 1);
    const size_t m0 = (size_t)bm * 128;
    const int j0b = jn * 256;
    const int wj = (w >> 1) * 64, wm2 = (w & 1) * 64;

    f32x4 acc[4][4];
#pragma unroll
    for (int a = 0; a < 4; ++a)
#pragma unroll
        for (int b = 0; b < 4; ++b) acc[a][b] = f32x4{0.f, 0.f, 0.f, 0.f};

    char* Acur = (char*)AbD[0];
    char* Anxt = (char*)AbD[1];
    char* Bcur = (char*)BbD[0];
    char* Bnxt = (char*)BbD[1];

#define STAGE_W(K0, BDST)                                                             \
    do {                                                                              \
        _Pragma("unroll")                                                             \
        for (int q = 0; q < 4; ++q) {                                                 \
            int idx = q * 512 + tid;                                                  \
            int jr = idx >> 3, sl = idx & 7;                                          \
            const _Float16* src = WTs + (size_t)(j0b + jr) * KP + (K0) + sl * 8;      \
            _Float16* dst = (_Float16*)(BDST) + (size_t)(q * 512 + w * 64) * 8;       \
            __builtin_amdgcn_global_load_lds(                                         \
                (const __attribute__((address_space(1))) void*)src,                   \
                (__attribute__((address_space(3))) void*)dst, 16, 0, 0);              \
        }                                                                             \
    } while (0)

#define LOAD_X(K0, XR)                                                                \
    do {                                                                              \
        _Pragma("unroll")                                                             \
        for (int c = 0; c < 4; ++c) {                                                 \
            int f = c * 512 + tid;                                                    \
            int mr = f >> 4, k4 = f & 15;                                             \
            if ((K0) + k4 * 4 + 3 < INF)                                              \
                XR[c] = *(const f4*)(x + (m0 + mr) * INF + (K0) + k4 * 4);            \
            else                                                                      \
                XR[c] = f4{0.f, 0.f, 0.f, 0.f};                                       \
        }                                                                             \
    } while (0)

#define WRITE_X(XR, ADST)                                                             \
    do {                                                                              \
        _Pragma("unroll")                                                             \
        for (int c = 0; c < 4; ++c) {                                                 \
            int f = c * 512 + tid;                                                    \
            int mr = f >> 4, k4 = f & 15;                                             \
            unsigned bo = (unsigned)mr * 128 + (((unsigned)k4 * 8) ^ ((mr & 7) << 4)); \
            *(h4*)((ADST) + bo) = h4{(_Float16)XR[c][0], (_Float16)XR[c][1],          \
                                     (_Float16)XR[c][2], (_Float16)XR[c][3]};         \
        }                                                                             \
    } while (0)

#define GBARRIER()                                                                    \
    do {                                                                              \
        __builtin_amdgcn_sched_barrier(0);                                            \
        asm volatile("s_waitcnt vmcnt(0) lgkmcnt(0)" ::: "memory");                   \
        __builtin_amdgcn_s_barrier();                                                 \
        __builtin_amdgcn_sched_barrier(0);                                            \
    } while (0)

    {
        f4 xr[4];
        LOAD_X(0, xr);
        STAGE_W(0, Bcur);
        asm volatile("s_waitcnt vmcnt(4)" ::: "memory");
        WRITE_X(xr, Acur);
        GBARRIER();
    }
    for (int s = 0; s < 5; ++s) {
        f4 xr[4];
        if (s < 4) {
            const int k0n = (s + 1) * 64;
            LOAD_X(k0n, xr);
            STAGE_W(k0n, Bnxt);
        }
#pragma unroll
        for (int kk = 0; kk < 2; ++kk) {
            h8 aw[4], bx[4];
#pragma unroll
            for (int jt = 0; jt < 4; ++jt) {
                int jr = wj + jt * 16 + lj;
                unsigned bo = (unsigned)jr * 128 + (((unsigned)(kk * 64 + lg * 16)) ^ ((jr & 7) << 4));
                aw[jt] = *(const h8*)(Bcur + bo);
            }
#pragma unroll
            for (int mt = 0; mt < 4; ++mt) {
                int mr = wm2 + mt * 16 + lj;
                unsigned bo = (unsigned)mr * 128 + (((unsigned)(kk * 64 + lg * 16)) ^ ((mr & 7) << 4));
                bx[mt] = *(const h8*)(Acur + bo);
            }
#pragma unroll
            for (int jt = 0; jt < 4; ++jt)
#pragma unroll
                for (int mt = 0; mt < 4; ++mt)
                    acc[jt][mt] = __builtin_amdgcn_mfma_f32_16x16x32_f16(aw[jt], bx[mt], acc[jt][mt], 0, 0, 0);
        }
        if (s < 4) {
            asm volatile("s_waitcnt vmcnt(4)" ::: "memory");
            WRITE_X(xr, Anxt);
        }
        GBARRIER();
        char* t0 = Acur; Acur = Anxt; Anxt = t0;
        char* t1 = Bcur; Bcur = Bnxt; Bnxt = t1;
    }
#undef STAGE_W
#undef LOAD_X
#undef WRITE_X
#undef GBARRIER

    f4 bias4[4];
#pragma unroll
    for (int jt = 0; jt < 4; ++jt)
        bias4[jt] = *(const f4*)(bcat + j0b + wj + jt * 16 + lg * 4);
    char* prc = (char*)pre3;
#pragma unroll
    for (int jt = 0; jt < 4; ++jt) {
        int slab = (j0b + wj + jt * 16) >> 4;
#pragma unroll
        for (int mt = 0; mt < 4; ++mt) {
            int M = (int)m0 + wm2 + mt * 16;
            size_t byte = (size_t)(M >> 8) * 262144 + (size_t)slab * 8192
                        + (size_t)((M & 255) + lj) * 32 + (size_t)lg * 8;
            h4 o;
#pragma unroll
            for (int i = 0; i < 4; ++i)
                o[i] = (_Float16)(acc[jt][mt][i] + bias4[jt][i]);
            *(h4*)(prc + byte) = o;
        }
    }
}

// ---------------- recurrence: R16-verified (lgkmcnt ladder) ----------------
__global__ __launch_bounds__(512, 2) void rnn_scan(
    const float* __restrict__ W1h, const float* __restrict__ W2h,
    const _Float16* __restrict__ pre3, float* __restrict__ hcat)
{
    __shared__ char hbs[16384];  // [2][8192]
    char* hbc = hbs;
    const int tid = threadIdx.x;
    const int w = tid >> 6, l = tid & 63;
    const int lj = l & 15, lg = l >> 4;
    const int dir = blockIdx.x & 1;
    const int b0 = (int)(blockIdx.x >> 1) * 16;
    const float* Wh = dir ? W2h : W1h;
    const int j0 = w * 32;
    const int dirOff = dir ? HID : 0;

    h8 afrag[2][8];
#pragma unroll
    for (int jt = 0; jt < 2; ++jt) {
        int jc = j0 + jt * 16 + lj;
#pragma unroll
        for (int kk = 0; kk < 8; ++kk) {
            h8 t;
#pragma unroll
            for (int i = 0; i < 8; ++i) t[i] = (_Float16)Wh[(kk * 32 + lg * 8 + i) * HID + jc];
            afrag[jt][kk] = t;
        }
    }

    const unsigned rb = (unsigned)l * 16;
    const unsigned wb0 = (unsigned)w * 1024 + (unsigned)(lg >> 1) * 256
                       + (unsigned)lj * 16 + (unsigned)(lg & 1) * 8;

    ((h8*)hbs)[tid] = h8{0, 0, 0, 0, 0, 0, 0, 0};
    __syncthreads();

    const long long sb = dir ? -262144LL : 262144LL;
    const char* pp = (const char*)pre3 + (long long)(dir ? (SEQL - 1) : 0) * 262144
                   + (long long)dir * 131072
                   + (long long)w * 16384 + (long long)(b0 + lj) * 32 + lg * 8;
    h4 pA[2], pB[2];
#pragma unroll
    for (int jt = 0; jt < 2; ++jt) pA[jt] = *(const h4*)(pp + jt * 8192);
    pp += sb;
#pragma unroll
    for (int jt = 0; jt < 2; ++jt) pB[jt] = *(const h4*)(pp + jt * 8192);
    pp += sb;

#define RD(KK, RB)                                                                    \
        bf[KK] = *(const h8*)(hbc + (RB) + (KK) * 1024 + rb);                         \
        __builtin_amdgcn_sched_barrier(0);

#define MM(KK, CNT)                                                                   \
        asm volatile("s_waitcnt lgkmcnt(" #CNT ")" ::: "memory");                     \
        __builtin_amdgcn_sched_barrier(0);                                            \
        acc0 = __builtin_amdgcn_mfma_f32_16x16x32_f16(afrag[0][KK], bf[KK], acc0, 0, 0, 0); \
        acc1 = __builtin_amdgcn_mfma_f32_16x16x32_f16(afrag[1][KK], bf[KK], acc1, 0, 0, 0);

#define RNN_STEP(RB, WB, P, DO_PF)                                                    \
    do {                                                                              \
        h8 bf[8];                                                                     \
        f32x4 acc0, acc1;                                                             \
        _Pragma("unroll")                                                             \
        for (int i = 0; i < 4; ++i) { acc0[i] = (float)P[0][i]; acc1[i] = (float)P[1][i]; } \
        __builtin_amdgcn_sched_barrier(0);                                            \
        RD(0, RB) RD(1, RB) RD(2, RB) RD(3, RB)                                       \
        RD(4, RB) RD(5, RB) RD(6, RB) RD(7, RB)                                       \
        if (DO_PF) {                                                                  \
            P[0] = *(const h4*)(pp);                                                  \
            P[1] = *(const h4*)(pp + 8192);                                           \
            pp += sb;                                                                 \
        }                                                                             \
        MM(0, 7) MM(1, 6) MM(2, 5) MM(3, 4)                                           \
        MM(4, 3) MM(5, 2) MM(6, 1) MM(7, 0)                                           \
        h4 o0, o1;                                                                    \
        _Pragma("unroll")                                                             \
        for (int i = 0; i < 4; ++i) o0[i] = (_Float16)ftanh(acc0[i]);                 \
        *(h4*)(hbc + (WB) + wb0) = o0;                                                \
        _Pragma("unroll")                                                             \
        for (int i = 0; i < 4; ++i) o1[i] = (_Float16)ftanh(acc1[i]);                 \
        *(h4*)(hbc + (WB) + wb0 + 512) = o1;                                          \
        __builtin_amdgcn_sched_barrier(0);                                            \
        asm volatile("s_waitcnt lgkmcnt(0)" ::: "memory");                            \
        __builtin_amdgcn_s_barrier();                                                 \
        __builtin_amdgcn_sched_barrier(0);                                            \
    } while (0)

    for (int tp = 0; tp < 255; ++tp) {
        RNN_STEP(0, 8192, pA, 1);
        RNN_STEP(8192, 0, pB, 1);
    }
    RNN_STEP(0, 8192, pA, 0);

    {
        f32x4 acc0, acc1;
#pragma unroll
        for (int i = 0; i < 4; ++i) { acc0[i] = (float)pB[0][i]; acc1[i] = (float)pB[1][i]; }
        h8 bf[8];
#pragma unroll
        for (int kk = 0; kk < 8; ++kk)
            bf[kk] = *(const h8*)(hbc + 8192 + kk * 1024 + rb);
#pragma unroll
        for (int kk = 0; kk < 8; ++kk) {
            acc0 = __builtin_amdgcn_mfma_f32_16x16x32_f16(afrag[0][kk], bf[kk], acc0, 0, 0, 0);
            acc1 = __builtin_amdgcn_mfma_f32_16x16x32_f16(afrag[1][kk], bf[kk], acc1, 0, 0, 0);
        }
        f4 v0, v1;
#pragma unroll
        for (int i = 0; i < 4; ++i) { v0[i] = ftanh(acc0[i]); v1[i] = ftanh(acc1[i]); }
        float* hc = hcat + (size_t)(b0 + lj) * N2 + dirOff + j0 + lg * 4;
        *(f4*)hc = v0;
        *(f4*)(hc + 16) = v1;
    }
#undef RNN_STEP
#undef MM
#undef RD
}

// ---------------- head: 64 blocks x 4 batch-rows (R6-verified) ----------------
__global__ __launch_bounds__(256) void head_mlp(
    const float* __restrict__ hcat,
    const float* __restrict__ fc1w, const float* __restrict__ fc1b,
    const float* __restrict__ fc2w, const float* __restrict__ fc2b,
    const float* __restrict__ fsw, const float* __restrict__ fsb,
    float* __restrict__ out)
{
    __shared__ float hs[4 * 512];
    __shared__ float y1[4 * 512];
    __shared__ float y2[4 * 256];
    const int tid = threadIdx.x;
    const int b0 = blockIdx.x * 4;
    const int r = tid >> 6;
    const int lane = tid & 63;

#pragma unroll
    for (int c = 0; c < 2; ++c)
        ((f4*)hs)[c * 256 + tid] = ((const f4*)(hcat + (size_t)b0 * N2))[c * 256 + tid];
    __syncthreads();

    {
        const int j0 = lane * 8;
        f4 a0 = *(const f4*)(fc1b + j0);
        f4 a1 = *(const f4*)(fc1b + j0 + 4);
        for (int k = 0; k < 512; ++k) {
            float h = hs[r * 512 + k];
            f4 w0 = *(const f4*)(fc1w + (size_t)k * 512 + j0);
            f4 w1 = *(const f4*)(fc1w + (size_t)k * 512 + j0 + 4);
#pragma unroll
            for (int i = 0; i < 4; ++i) { a0[i] = fmaf(h, w0[i], a0[i]); a1[i] = fmaf(h, w1[i], a1[i]); }
        }
#pragma unroll
        for (int i = 0; i < 4; ++i) {
            y1[r * 512 + j0 + i]     = fmaxf(a0[i], 0.f);
            y1[r * 512 + j0 + 4 + i] = fmaxf(a1[i], 0.f);
        }
    }
    __syncthreads();

    {
        const int j2 = lane * 4;
        f4 a = *(const f4*)(fc2b + j2);
        for (int k = 0; k < 512; ++k) {
            float yv = y1[r * 512 + k];
            f4 w = *(const f4*)(fc2w + (size_t)k * 256 + j2);
#pragma unroll
            for (int i = 0; i < 4; ++i) a[i] = fmaf(yv, w[i], a[i]);
        }
#pragma unroll
        for (int i = 0; i < 4; ++i) y2[r * 256 + j2 + i] = fmaxf(a[i], 0.f);
    }
    __syncthreads();

    {
        float p = 0.f;
#pragma unroll
        for (int u = 0; u < 4; ++u)
            p = fmaf(y2[r * 256 + lane + u * 64], fsw[lane + u * 64], p);
#pragma unroll
        for (int off = 32; off > 0; off >>= 1) p += __shfl_down(p, off);
        if (lane == 0) out[b0 + r] = ftanh(p + fsb[0]);
    }
}

extern "C" void kernel_launch(void* const* d_in, const int* in_sizes, int n_in,
                              void* d_out, int out_size, void* d_ws, size_t ws_size,
                              hipStream_t stream)
{
    const float* x    = (const float*)d_in[0];
    const float* W1x  = (const float*)d_in[1];
    const float* W1h  = (const float*)d_in[2];
    const float* b1   = (const float*)d_in[3];
    const float* W2x  = (const float*)d_in[4];
    const float* W2h  = (const float*)d_in[5];
    const float* b2   = (const float*)d_in[6];
    const float* fc1w = (const float*)d_in[7];
    const float* fc1b = (const float*)d_in[8];
    const float* fc2w = (const float*)d_in[9];
    const float* fc2b = (const float*)d_in[10];
    const float* fsw  = (const float*)d_in[11];
    const float* fsb  = (const float*)d_in[12];

    char* ws = (char*)d_ws;
    size_t off = 0;
    _Float16* WTs  = (_Float16*)(ws + off); off += (size_t)N2 * KP * sizeof(_Float16);
    float* bcat    = (float*)(ws + off);    off += (size_t)N2 * sizeof(float);
    float* hcat    = (float*)(ws + off);    off += (size_t)BATCH * N2 * sizeof(float);
    _Float16* pre3 = (_Float16*)(ws + off); off += (size_t)SEQL * BATCH * N2 * sizeof(_Float16);
    if (off > ws_size) return;

    prep_kernel<<<(N2 * KP + 255) / 256, 256, 0, stream>>>(W1x, W2x, b1, b2, WTs, bcat);

    static hipError_t attr_err = hipFuncSetAttribute(
        (const void*)gemm_persist, hipFuncAttributeMaxDynamicSharedMemorySize, 114688);
    if (attr_err == hipSuccess) {
        gemm_persist<<<256, 512, 114688, stream>>>(x, WTs, bcat, pre3);
    } else {
        gemm_pre<<<2048, 512, 0, stream>>>(x, WTs, bcat, pre3);
    }
    rnn_scan<<<(BATCH / 16) * 2, 512, 0, stream>>>(W1h, W2h, pre3, hcat);
    head_mlp<<<64, 256, 0, stream>>>(hcat, fc1w, fc1b, fc2w, fc2b, fsw, fsb, (float*)d_out);
}

// Round 18
// 479.763 us; speedup vs baseline: 1.1002x; 1.1002x over previous
//
#include <hip/hip_runtime.h>

#define DI __device__ __forceinline__

typedef float f32x4 __attribute__((ext_vector_type(4)));
typedef float f4    __attribute__((ext_vector_type(4)));
typedef _Float16 h8 __attribute__((ext_vector_type(8)));
typedef _Float16 h4 __attribute__((ext_vector_type(4)));

// sizes
#define SEQL 512
#define BATCH 256
#define INF 300
#define HID 256
#define N2 512   // 2*HID
#define KP 320   // INF padded to multiple of 64

// pre3 layout: element (t, j, b) at byte t*262144 + (j>>4)*8192 + b*32 + (j&15)*2

DI float ftanh(float x) {
    float e = __builtin_amdgcn_exp2f(x * 2.8853900817779268f);
    return fmaf(-2.0f, __builtin_amdgcn_rcpf(e + 1.0f), 1.0f);
}

// ---------------- prep: WcatT (xor-swizzled f16) + bcat ----------------
__global__ void prep_kernel(const float* __restrict__ W1x, const float* __restrict__ W2x,
                            const float* __restrict__ b1, const float* __restrict__ b2,
                            _Float16* __restrict__ WTs, float* __restrict__ bcat)
{
    int idx = blockIdx.x * 256 + threadIdx.x;
    if (idx < N2 * KP) {
        int j = idx / KP, z = idx - j * KP;
        int k = z ^ ((j & 7) << 3);
        float v = 0.f;
        if (k < INF) v = (j < HID) ? W1x[k * HID + j] : W2x[k * HID + (j - HID)];
        WTs[j * KP + z] = (_Float16)v;
    }
    if (idx < N2) bcat[idx] = (idx < HID) ? b1[idx] : b2[idx - HID];
}

// ---------------- GEMM: 128m x 128j, dbuf + 2 blocks/CU ----------------
// 4096 blocks x 256 threads (4 waves, 2x2 of 64x64), BK=64, XCD-grouped swizzle.
// 4 x 16KB LDS buffers (64KB) -> 2 blocks/CU: intra-block dbuf latency hiding AND
// an independent co-resident block to fill barrier drains. R6/R13-verified addressing.
__global__ __launch_bounds__(256, 2) void gemm_pre(
    const float* __restrict__ x, const _Float16* __restrict__ WTs,
    const float* __restrict__ bcat, _Float16* __restrict__ pre3)
{
    __shared__ _Float16 AbD[2][128 * 64];  // 2 x 16KB x tile, xor-swizzled rows
    __shared__ _Float16 BbD[2][128 * 64];  // 2 x 16KB W tile, xor-swizzled rows
    const int tid = threadIdx.x;
    const int w = tid >> 6, l = tid & 63;
    const int lj = l & 15, lg = l >> 4;
    const int bid = blockIdx.x;
    const int xcd = bid & 7;
    const int idx0 = bid >> 3;
    const int bn = idx0 & 3;
    const int bm = xcd * 128 + (idx0 >> 2);
    const size_t m0 = (size_t)bm * 128;
    const int j0b = bn * 128;
    const int wj = (w >> 1) * 64, wm2 = (w & 1) * 64;

    f32x4 acc[4][4];  // [jt][mt]
#pragma unroll
    for (int a = 0; a < 4; ++a)
#pragma unroll
        for (int b = 0; b < 4; ++b) acc[a][b] = f32x4{0.f, 0.f, 0.f, 0.f};

    char* Acur = (char*)AbD[0];
    char* Anxt = (char*)AbD[1];
    char* Bcur = (char*)BbD[0];
    char* Bnxt = (char*)BbD[1];

#define STAGE_W(K0, BDST)                                                             \
    do {                                                                              \
        _Pragma("unroll")                                                             \
        for (int q = 0; q < 4; ++q) {                                                 \
            int idx = (w * 4 + q) * 64 + l;                                           \
            int jr = idx >> 3, sl = idx & 7;                                          \
            const _Float16* src = WTs + (size_t)(j0b + jr) * KP + (K0) + sl * 8;      \
            _Float16* dst = (_Float16*)(BDST) + (size_t)((w * 4 + q) * 64) * 8;       \
            __builtin_amdgcn_global_load_lds(                                         \
                (const __attribute__((address_space(1))) void*)src,                   \
                (__attribute__((address_space(3))) void*)dst, 16, 0, 0);              \
        }                                                                             \
    } while (0)

#define LOAD_X(K0, XR)                                                                \
    do {                                                                              \
        _Pragma("unroll")                                                             \
        for (int c = 0; c < 8; ++c) {                                                 \
            int f = c * 256 + tid;                                                    \
            int mr = f >> 4, k4 = f & 15;                                             \
            if ((K0) + k4 * 4 + 3 < INF)                                              \
                XR[c] = *(const f4*)(x + (m0 + mr) * INF + (K0) + k4 * 4);            \
            else                                                                      \
                XR[c] = f4{0.f, 0.f, 0.f, 0.f};                                       \
        }                                                                             \
    } while (0)

#define WRITE_X(XR, ADST)                                                             \
    do {                                                                              \
        _Pragma("unroll")                                                             \
        for (int c = 0; c < 8; ++c) {                                                 \
            int f = c * 256 + tid;                                                    \
            int mr = f >> 4, k4 = f & 15;                                             \
            unsigned bo = (unsigned)mr * 128 + (((unsigned)k4 * 8) ^ ((mr & 7) << 4)); \
            *(h4*)((ADST) + bo) = h4{(_Float16)XR[c][0], (_Float16)XR[c][1],          \
                                     (_Float16)XR[c][2], (_Float16)XR[c][3]};         \
        }                                                                             \
    } while (0)

#define GBARRIER()                                                                    \
    do {                                                                              \
        __builtin_amdgcn_sched_barrier(0);                                            \
        asm volatile("s_waitcnt vmcnt(0) lgkmcnt(0)" ::: "memory");                   \
        __builtin_amdgcn_s_barrier();                                                 \
        __builtin_amdgcn_sched_barrier(0);                                            \
    } while (0)

    // ---- prologue: stage tile 0 ----
    {
        f4 xr[8];
        LOAD_X(0, xr);
        STAGE_W(0, Bcur);
        asm volatile("s_waitcnt vmcnt(4)" ::: "memory");  // x regs ready, W DMA flying
        WRITE_X(xr, Acur);
        GBARRIER();
    }

    // ---- pipelined main loop ----
    for (int s = 0; s < 5; ++s) {
        f4 xr[8];
        if (s < 4) {
            const int k0n = (s + 1) * 64;
            LOAD_X(k0n, xr);      // 8 x-loads in flight (oldest)
            STAGE_W(k0n, Bnxt);   // 4 W-DMAs into next buffer
        }
        // compute tile s from cur
#pragma unroll
        for (int kk = 0; kk < 2; ++kk) {
            h8 aw[4], bx[4];
#pragma unroll
            for (int jt = 0; jt < 4; ++jt) {
                int jr = wj + jt * 16 + lj;
                unsigned bo = (unsigned)jr * 128 + (((unsigned)(kk * 64 + lg * 16)) ^ ((jr & 7) << 4));
                aw[jt] = *(const h8*)(Bcur + bo);
            }
#pragma unroll
            for (int mt = 0; mt < 4; ++mt) {
                int mr = wm2 + mt * 16 + lj;
                unsigned bo = (unsigned)mr * 128 + (((unsigned)(kk * 64 + lg * 16)) ^ ((mr & 7) << 4));
                bx[mt] = *(const h8*)(Acur + bo);
            }
#pragma unroll
            for (int jt = 0; jt < 4; ++jt)
#pragma unroll
                for (int mt = 0; mt < 4; ++mt)
                    acc[jt][mt] = __builtin_amdgcn_mfma_f32_16x16x32_f16(aw[jt], bx[mt], acc[jt][mt], 0, 0, 0);
        }
        if (s < 4) {
            asm volatile("s_waitcnt vmcnt(4)" ::: "memory");  // x regs ready; W DMA flying
            WRITE_X(xr, Anxt);
        }
        GBARRIER();
        char* t0 = Acur; Acur = Anxt; Anxt = t0;
        char* t1 = Bcur; Bcur = Bnxt; Bnxt = t1;
    }
#undef STAGE_W
#undef LOAD_X
#undef WRITE_X
#undef GBARRIER

    // epilogue: bias + 16 coalesced 8B stores into pre3
    f4 bias4[4];
#pragma unroll
    for (int jt = 0; jt < 4; ++jt)
        bias4[jt] = *(const f4*)(bcat + j0b + wj + jt * 16 + lg * 4);
    char* prc = (char*)pre3;
#pragma unroll
    for (int jt = 0; jt < 4; ++jt) {
        int slab = (j0b + wj + jt * 16) >> 4;
#pragma unroll
        for (int mt = 0; mt < 4; ++mt) {
            int M = (int)m0 + wm2 + mt * 16;
            size_t byte = (size_t)(M >> 8) * 262144 + (size_t)slab * 8192
                        + (size_t)((M & 255) + lj) * 32 + (size_t)lg * 8;
            h4 o;
#pragma unroll
            for (int i = 0; i < 4; ++i)
                o[i] = (_Float16)(acc[jt][mt][i] + bias4[jt][i]);
            *(h4*)(prc + byte) = o;
        }
    }
}

// ---------------- recurrence: R16-verified (lgkmcnt ladder), unchanged ----------------
__global__ __launch_bounds__(512, 2) void rnn_scan(
    const float* __restrict__ W1h, const float* __restrict__ W2h,
    const _Float16* __restrict__ pre3, float* __restrict__ hcat)
{
    __shared__ char hbs[16384];  // [2][8192]
    char* hbc = hbs;
    const int tid = threadIdx.x;
    const int w = tid >> 6, l = tid & 63;
    const int lj = l & 15, lg = l >> 4;
    const int dir = blockIdx.x & 1;
    const int b0 = (int)(blockIdx.x >> 1) * 16;
    const float* Wh = dir ? W2h : W1h;
    const int j0 = w * 32;
    const int dirOff = dir ? HID : 0;

    h8 afrag[2][8];
#pragma unroll
    for (int jt = 0; jt < 2; ++jt) {
        int jc = j0 + jt * 16 + lj;
#pragma unroll
        for (int kk = 0; kk < 8; ++kk) {
            h8 t;
#pragma unroll
            for (int i = 0; i < 8; ++i) t[i] = (_Float16)Wh[(kk * 32 + lg * 8 + i) * HID + jc];
            afrag[jt][kk] = t;
        }
    }

    const unsigned rb = (unsigned)l * 16;
    const unsigned wb0 = (unsigned)w * 1024 + (unsigned)(lg >> 1) * 256
                       + (unsigned)lj * 16 + (unsigned)(lg & 1) * 8;

    ((h8*)hbs)[tid] = h8{0, 0, 0, 0, 0, 0, 0, 0};
    __syncthreads();

    const long long sb = dir ? -262144LL : 262144LL;
    const char* pp = (const char*)pre3 + (long long)(dir ? (SEQL - 1) : 0) * 262144
                   + (long long)dir * 131072
                   + (long long)w * 16384 + (long long)(b0 + lj) * 32 + lg * 8;
    h4 pA[2], pB[2];
#pragma unroll
    for (int jt = 0; jt < 2; ++jt) pA[jt] = *(const h4*)(pp + jt * 8192);
    pp += sb;
#pragma unroll
    for (int jt = 0; jt < 2; ++jt) pB[jt] = *(const h4*)(pp + jt * 8192);
    pp += sb;

#define RD(KK, RB)                                                                    \
        bf[KK] = *(const h8*)(hbc + (RB) + (KK) * 1024 + rb);                         \
        __builtin_amdgcn_sched_barrier(0);

#define MM(KK, CNT)                                                                   \
        asm volatile("s_waitcnt lgkmcnt(" #CNT ")" ::: "memory");                     \
        __builtin_amdgcn_sched_barrier(0);                                            \
        acc0 = __builtin_amdgcn_mfma_f32_16x16x32_f16(afrag[0][KK], bf[KK], acc0, 0, 0, 0); \
        acc1 = __builtin_amdgcn_mfma_f32_16x16x32_f16(afrag[1][KK], bf[KK], acc1, 0, 0, 0);

#define RNN_STEP(RB, WB, P, DO_PF)                                                    \
    do {                                                                              \
        h8 bf[8];                                                                     \
        f32x4 acc0, acc1;                                                             \
        _Pragma("unroll")                                                             \
        for (int i = 0; i < 4; ++i) { acc0[i] = (float)P[0][i]; acc1[i] = (float)P[1][i]; } \
        __builtin_amdgcn_sched_barrier(0);                                            \
        RD(0, RB) RD(1, RB) RD(2, RB) RD(3, RB)                                       \
        RD(4, RB) RD(5, RB) RD(6, RB) RD(7, RB)                                       \
        if (DO_PF) {                                                                  \
            P[0] = *(const h4*)(pp);                                                  \
            P[1] = *(const h4*)(pp + 8192);                                           \
            pp += sb;                                                                 \
        }                                                                             \
        MM(0, 7) MM(1, 6) MM(2, 5) MM(3, 4)                                           \
        MM(4, 3) MM(5, 2) MM(6, 1) MM(7, 0)                                           \
        h4 o0, o1;                                                                    \
        _Pragma("unroll")                                                             \
        for (int i = 0; i < 4; ++i) o0[i] = (_Float16)ftanh(acc0[i]);                 \
        *(h4*)(hbc + (WB) + wb0) = o0;                                                \
        _Pragma("unroll")                                                             \
        for (int i = 0; i < 4; ++i) o1[i] = (_Float16)ftanh(acc1[i]);                 \
        *(h4*)(hbc + (WB) + wb0 + 512) = o1;                                          \
        __builtin_amdgcn_sched_barrier(0);                                            \
        asm volatile("s_waitcnt lgkmcnt(0)" ::: "memory");                            \
        __builtin_amdgcn_s_barrier();                                                 \
        __builtin_amdgcn_sched_barrier(0);                                            \
    } while (0)

    for (int tp = 0; tp < 255; ++tp) {
        RNN_STEP(0, 8192, pA, 1);
        RNN_STEP(8192, 0, pB, 1);
    }
    RNN_STEP(0, 8192, pA, 0);

    {
        f32x4 acc0, acc1;
#pragma unroll
        for (int i = 0; i < 4; ++i) { acc0[i] = (float)pB[0][i]; acc1[i] = (float)pB[1][i]; }
        h8 bf[8];
#pragma unroll
        for (int kk = 0; kk < 8; ++kk)
            bf[kk] = *(const h8*)(hbc + 8192 + kk * 1024 + rb);
#pragma unroll
        for (int kk = 0; kk < 8; ++kk) {
            acc0 = __builtin_amdgcn_mfma_f32_16x16x32_f16(afrag[0][kk], bf[kk], acc0, 0, 0, 0);
            acc1 = __builtin_amdgcn_mfma_f32_16x16x32_f16(afrag[1][kk], bf[kk], acc1, 0, 0, 0);
        }
        f4 v0, v1;
#pragma unroll
        for (int i = 0; i < 4; ++i) { v0[i] = ftanh(acc0[i]); v1[i] = ftanh(acc1[i]); }
        float* hc = hcat + (size_t)(b0 + lj) * N2 + dirOff + j0 + lg * 4;
        *(f4*)hc = v0;
        *(f4*)(hc + 16) = v1;
    }
#undef RNN_STEP
#undef MM
#undef RD
}

// ---------------- head: 64 blocks x 4 batch-rows (R6-verified) ----------------
__global__ __launch_bounds__(256) void head_mlp(
    const float* __restrict__ hcat,
    const float* __restrict__ fc1w, const float* __restrict__ fc1b,
    const float* __restrict__ fc2w, const float* __restrict__ fc2b,
    const float* __restrict__ fsw, const float* __restrict__ fsb,
    float* __restrict__ out)
{
    __shared__ float hs[4 * 512];
    __shared__ float y1[4 * 512];
    __shared__ float y2[4 * 256];
    const int tid = threadIdx.x;
    const int b0 = blockIdx.x * 4;
    const int r = tid >> 6;
    const int lane = tid & 63;

#pragma unroll
    for (int c = 0; c < 2; ++c)
        ((f4*)hs)[c * 256 + tid] = ((const f4*)(hcat + (size_t)b0 * N2))[c * 256 + tid];
    __syncthreads();

    {
        const int j0 = lane * 8;
        f4 a0 = *(const f4*)(fc1b + j0);
        f4 a1 = *(const f4*)(fc1b + j0 + 4);
        for (int k = 0; k < 512; ++k) {
            float h = hs[r * 512 + k];
            f4 w0 = *(const f4*)(fc1w + (size_t)k * 512 + j0);
            f4 w1 = *(const f4*)(fc1w + (size_t)k * 512 + j0 + 4);
#pragma unroll
            for (int i = 0; i < 4; ++i) { a0[i] = fmaf(h, w0[i], a0[i]); a1[i] = fmaf(h, w1[i], a1[i]); }
        }
#pragma unroll
        for (int i = 0; i < 4; ++i) {
            y1[r * 512 + j0 + i]     = fmaxf(a0[i], 0.f);
            y1[r * 512 + j0 + 4 + i] = fmaxf(a1[i], 0.f);
        }
    }
    __syncthreads();

    {
        const int j2 = lane * 4;
        f4 a = *(const f4*)(fc2b + j2);
        for (int k = 0; k < 512; ++k) {
            float yv = y1[r * 512 + k];
            f4 w = *(const f4*)(fc2w + (size_t)k * 256 + j2);
#pragma unroll
            for (int i = 0; i < 4; ++i) a[i] = fmaf(yv, w[i], a[i]);
        }
#pragma unroll
        for (int i = 0; i < 4; ++i) y2[r * 256 + j2 + i] = fmaxf(a[i], 0.f);
    }
    __syncthreads();

    {
        float p = 0.f;
#pragma unroll
        for (int u = 0; u < 4; ++u)
            p = fmaf(y2[r * 256 + lane + u * 64], fsw[lane + u * 64], p);
#pragma unroll
        for (int off = 32; off > 0; off >>= 1) p += __shfl_down(p, off);
        if (lane == 0) out[b0 + r] = ftanh(p + fsb[0]);
    }
}

extern "C" void kernel_launch(void* const* d_in, const int* in_sizes, int n_in,
                              void* d_out, int out_size, void* d_ws, size_t ws_size,
                              hipStream_t stream)
{
    const float* x    = (const float*)d_in[0];
    const float* W1x  = (const float*)d_in[1];
    const float* W1h  = (const float*)d_in[2];
    const float* b1   = (const float*)d_in[3];
    const float* W2x  = (const float*)d_in[4];
    const float* W2h  = (const float*)d_in[5];
    const float* b2   = (const float*)d_in[6];
    const float* fc1w = (const float*)d_in[7];
    const float* fc1b = (const float*)d_in[8];
    const float* fc2w = (const float*)d_in[9];
    const float* fc2b = (const float*)d_in[10];
    const float* fsw  = (const float*)d_in[11];
    const float* fsb  = (const float*)d_in[12];

    char* ws = (char*)d_ws;
    size_t off = 0;
    _Float16* WTs  = (_Float16*)(ws + off); off += (size_t)N2 * KP * sizeof(_Float16);
    float* bcat    = (float*)(ws + off);    off += (size_t)N2 * sizeof(float);
    float* hcat    = (float*)(ws + off);    off += (size_t)BATCH * N2 * sizeof(float);
    _Float16* pre3 = (_Float16*)(ws + off); off += (size_t)SEQL * BATCH * N2 * sizeof(_Float16);
    if (off > ws_size) return;

    prep_kernel<<<(N2 * KP + 255) / 256, 256, 0, stream>>>(W1x, W2x, b1, b2, WTs, bcat);
    gemm_pre<<<4096, 256, 0, stream>>>(x, WTs, bcat, pre3);
    rnn_scan<<<(BATCH / 16) * 2, 512, 0, stream>>>(W1h, W2h, pre3, hcat);
    head_mlp<<<64, 256, 0, stream>>>(hcat, fc1w, fc1b, fc2w, fc2b, fsw, fsb, (float*)d_out);
}

// Round 19
// 471.337 us; speedup vs baseline: 1.1199x; 1.0179x over previous
//
#include <hip/hip_runtime.h>

#define DI __device__ __forceinline__

typedef float f32x4 __attribute__((ext_vector_type(4)));
typedef float f4    __attribute__((ext_vector_type(4)));
typedef _Float16 h8 __attribute__((ext_vector_type(8)));
typedef _Float16 h4 __attribute__((ext_vector_type(4)));

// sizes
#define SEQL 512
#define BATCH 256
#define INF 300
#define HID 256
#define N2 512   // 2*HID
#define KP 320   // INF padded to multiple of 64

// pre3 layout: element (t, j, b) at byte t*262144 + (j>>4)*8192 + b*32 + (j&15)*2

DI float ftanh(float x) {
    float e = __builtin_amdgcn_exp2f(x * 2.8853900817779268f);
    return fmaf(-2.0f, __builtin_amdgcn_rcpf(e + 1.0f), 1.0f);
}

// ---------------- prep: WcatT (xor-swizzled f16) + bcat ----------------
__global__ void prep_kernel(const float* __restrict__ W1x, const float* __restrict__ W2x,
                            const float* __restrict__ b1, const float* __restrict__ b2,
                            _Float16* __restrict__ WTs, float* __restrict__ bcat)
{
    int idx = blockIdx.x * 256 + threadIdx.x;
    if (idx < N2 * KP) {
        int j = idx / KP, z = idx - j * KP;
        int k = z ^ ((j & 7) << 3);
        float v = 0.f;
        if (k < INF) v = (j < HID) ? W1x[k * HID + j] : W2x[k * HID + (j - HID)];
        WTs[j * KP + z] = (_Float16)v;
    }
    if (idx < N2) bcat[idx] = (idx < HID) ? b1[idx] : b2[idx - HID];
}

// ---------------- GEMM: pre3 = x @ Wcat + bcat, double-buffered (R16-best) ----------------
// 128m x 256j tile, 8 waves, BK=64, 2048 blocks, XCD-grouped swizzle.
// LOAD_X issued before STAGE_W; mid-step wait is vmcnt(4) (x regs only),
// W-DMA keeps flying until the pre-barrier drain.
__global__ __launch_bounds__(512, 2) void gemm_pre(
    const float* __restrict__ x, const _Float16* __restrict__ WTs,
    const float* __restrict__ bcat, _Float16* __restrict__ pre3)
{
    __shared__ _Float16 AbD[2][128 * 64];  // 2 x 16KB x tile, xor-swizzled rows
    __shared__ _Float16 BbD[2][256 * 64];  // 2 x 32KB W tile, xor-swizzled rows
    const int tid = threadIdx.x;
    const int w = tid >> 6, l = tid & 63;
    const int lj = l & 15, lg = l >> 4;
    const int bid = blockIdx.x;
    const int xcd = bid & 7;
    const int idx0 = bid >> 3;
    const int jn = idx0 & 1;
    const int bm = xcd * 128 + (idx0 >> 1);
    const size_t m0 = (size_t)bm * 128;
    const int j0b = jn * 256;
    const int wj = (w >> 1) * 64, wm2 = (w & 1) * 64;

    f32x4 acc[4][4];  // [jt][mt]
#pragma unroll
    for (int a = 0; a < 4; ++a)
#pragma unroll
        for (int b = 0; b < 4; ++b) acc[a][b] = f32x4{0.f, 0.f, 0.f, 0.f};

    char* Acur = (char*)AbD[0];
    char* Anxt = (char*)AbD[1];
    char* Bcur = (char*)BbD[0];
    char* Bnxt = (char*)BbD[1];

#define STAGE_W(K0, BDST)                                                             \
    do {                                                                              \
        _Pragma("unroll")                                                             \
        for (int q = 0; q < 4; ++q) {                                                 \
            int idx = q * 512 + tid;                                                  \
            int jr = idx >> 3, sl = idx & 7;                                          \
            const _Float16* src = WTs + (size_t)(j0b + jr) * KP + (K0) + sl * 8;      \
            _Float16* dst = (_Float16*)(BDST) + (size_t)(q * 512 + w * 64) * 8;       \
            __builtin_amdgcn_global_load_lds(                                         \
                (const __attribute__((address_space(1))) void*)src,                   \
                (__attribute__((address_space(3))) void*)dst, 16, 0, 0);              \
        }                                                                             \
    } while (0)

#define LOAD_X(K0, XR)                                                                \
    do {                                                                              \
        _Pragma("unroll")                                                             \
        for (int c = 0; c < 4; ++c) {                                                 \
            int f = c * 512 + tid;                                                    \
            int mr = f >> 4, k4 = f & 15;                                             \
            if ((K0) + k4 * 4 + 3 < INF)                                              \
                XR[c] = *(const f4*)(x + (m0 + mr) * INF + (K0) + k4 * 4);            \
            else                                                                      \
                XR[c] = f4{0.f, 0.f, 0.f, 0.f};                                       \
        }                                                                             \
    } while (0)

#define WRITE_X(XR, ADST)                                                             \
    do {                                                                              \
        _Pragma("unroll")                                                             \
        for (int c = 0; c < 4; ++c) {                                                 \
            int f = c * 512 + tid;                                                    \
            int mr = f >> 4, k4 = f & 15;                                             \
            unsigned bo = (unsigned)mr * 128 + (((unsigned)k4 * 8) ^ ((mr & 7) << 4)); \
            *(h4*)((ADST) + bo) = h4{(_Float16)XR[c][0], (_Float16)XR[c][1],          \
                                     (_Float16)XR[c][2], (_Float16)XR[c][3]};         \
        }                                                                             \
    } while (0)

#define GBARRIER()                                                                    \
    do {                                                                              \
        __builtin_amdgcn_sched_barrier(0);                                            \
        asm volatile("s_waitcnt vmcnt(0) lgkmcnt(0)" ::: "memory");                   \
        __builtin_amdgcn_s_barrier();                                                 \
        __builtin_amdgcn_sched_barrier(0);                                            \
    } while (0)

    // ---- prologue: stage tile 0 ----
    {
        f4 xr[4];
        LOAD_X(0, xr);
        STAGE_W(0, Bcur);
        asm volatile("s_waitcnt vmcnt(4)" ::: "memory");  // x regs ready, W DMA flying
        WRITE_X(xr, Acur);
        GBARRIER();  // drains W DMA too
    }

    // ---- pipelined main loop ----
    for (int s = 0; s < 5; ++s) {
        f4 xr[4];
        if (s < 4) {
            const int k0n = (s + 1) * 64;
            LOAD_X(k0n, xr);      // x regs in flight (oldest)
            STAGE_W(k0n, Bnxt);   // DMA into next buffer
        }
#pragma unroll
        for (int kk = 0; kk < 2; ++kk) {
            h8 aw[4], bx[4];
#pragma unroll
            for (int jt = 0; jt < 4; ++jt) {
                int jr = wj + jt * 16 + lj;
                unsigned bo = (unsigned)jr * 128 + (((unsigned)(kk * 64 + lg * 16)) ^ ((jr & 7) << 4));
                aw[jt] = *(const h8*)(Bcur + bo);
            }
#pragma unroll
            for (int mt = 0; mt < 4; ++mt) {
                int mr = wm2 + mt * 16 + lj;
                unsigned bo = (unsigned)mr * 128 + (((unsigned)(kk * 64 + lg * 16)) ^ ((mr & 7) << 4));
                bx[mt] = *(const h8*)(Acur + bo);
            }
#pragma unroll
            for (int jt = 0; jt < 4; ++jt)
#pragma unroll
                for (int mt = 0; mt < 4; ++mt)
                    acc[jt][mt] = __builtin_amdgcn_mfma_f32_16x16x32_f16(aw[jt], bx[mt], acc[jt][mt], 0, 0, 0);
        }
        if (s < 4) {
            asm volatile("s_waitcnt vmcnt(4)" ::: "memory");  // x regs ready; W DMA flying
            WRITE_X(xr, Anxt);
        }
        GBARRIER();
        char* t0 = Acur; Acur = Anxt; Anxt = t0;
        char* t1 = Bcur; Bcur = Bnxt; Bnxt = t1;
    }
#undef STAGE_W
#undef LOAD_X
#undef WRITE_X
#undef GBARRIER

    // epilogue: bias + 16 coalesced 8B stores into pre3
    f4 bias4[4];
#pragma unroll
    for (int jt = 0; jt < 4; ++jt)
        bias4[jt] = *(const f4*)(bcat + j0b + wj + jt * 16 + lg * 4);
    char* prc = (char*)pre3;
#pragma unroll
    for (int jt = 0; jt < 4; ++jt) {
        int slab = (j0b + wj + jt * 16) >> 4;
#pragma unroll
        for (int mt = 0; mt < 4; ++mt) {
            int M = (int)m0 + wm2 + mt * 16;
            size_t byte = (size_t)(M >> 8) * 262144 + (size_t)slab * 8192
                        + (size_t)((M & 255) + lj) * 32 + (size_t)lg * 8;
            h4 o;
#pragma unroll
            for (int i = 0; i < 4; ++i)
                o[i] = (_Float16)(acc[jt][mt][i] + bias4[jt][i]);
            *(h4*)(prc + byte) = o;
        }
    }
}

// ---------------- recurrence: 32 blocks x 8 waves, explicit lgkmcnt ladder ----------------
__global__ __launch_bounds__(512, 2) void rnn_scan(
    const float* __restrict__ W1h, const float* __restrict__ W2h,
    const _Float16* __restrict__ pre3, float* __restrict__ hcat)
{
    __shared__ char hbs[16384];  // [2][8192]
    char* hbc = hbs;
    const int tid = threadIdx.x;
    const int w = tid >> 6, l = tid & 63;
    const int lj = l & 15, lg = l >> 4;
    const int dir = blockIdx.x & 1;
    const int b0 = (int)(blockIdx.x >> 1) * 16;
    const float* Wh = dir ? W2h : W1h;
    const int j0 = w * 32;
    const int dirOff = dir ? HID : 0;

    h8 afrag[2][8];
#pragma unroll
    for (int jt = 0; jt < 2; ++jt) {
        int jc = j0 + jt * 16 + lj;
#pragma unroll
        for (int kk = 0; kk < 8; ++kk) {
            h8 t;
#pragma unroll
            for (int i = 0; i < 8; ++i) t[i] = (_Float16)Wh[(kk * 32 + lg * 8 + i) * HID + jc];
            afrag[jt][kk] = t;
        }
    }

    const unsigned rb = (unsigned)l * 16;
    const unsigned wb0 = (unsigned)w * 1024 + (unsigned)(lg >> 1) * 256
                       + (unsigned)lj * 16 + (unsigned)(lg & 1) * 8;

    ((h8*)hbs)[tid] = h8{0, 0, 0, 0, 0, 0, 0, 0};
    __syncthreads();

    const long long sb = dir ? -262144LL : 262144LL;
    const char* pp = (const char*)pre3 + (long long)(dir ? (SEQL - 1) : 0) * 262144
                   + (long long)dir * 131072
                   + (long long)w * 16384 + (long long)(b0 + lj) * 32 + lg * 8;
    h4 pA[2], pB[2];
#pragma unroll
    for (int jt = 0; jt < 2; ++jt) pA[jt] = *(const h4*)(pp + jt * 8192);
    pp += sb;
#pragma unroll
    for (int jt = 0; jt < 2; ++jt) pB[jt] = *(const h4*)(pp + jt * 8192);
    pp += sb;

// one pinned ds_read issue
#define RD(KK, RB)                                                                    \
        bf[KK] = *(const h8*)(hbc + (RB) + (KK) * 1024 + rb);                         \
        __builtin_amdgcn_sched_barrier(0);

// wait for read KK (7-KK still outstanding), then its MFMA pair
#define MM(KK, CNT)                                                                   \
        asm volatile("s_waitcnt lgkmcnt(" #CNT ")" ::: "memory");                     \
        __builtin_amdgcn_sched_barrier(0);                                            \
        acc0 = __builtin_amdgcn_mfma_f32_16x16x32_f16(afrag[0][KK], bf[KK], acc0, 0, 0, 0); \
        acc1 = __builtin_amdgcn_mfma_f32_16x16x32_f16(afrag[1][KK], bf[KK], acc1, 0, 0, 0);

#define RNN_STEP(RB, WB, P, DO_PF)                                                    \
    do {                                                                              \
        h8 bf[8];                                                                     \
        f32x4 acc0, acc1;                                                             \
        _Pragma("unroll")                                                             \
        for (int i = 0; i < 4; ++i) { acc0[i] = (float)P[0][i]; acc1[i] = (float)P[1][i]; } \
        __builtin_amdgcn_sched_barrier(0);                                            \
        RD(0, RB) RD(1, RB) RD(2, RB) RD(3, RB)                                       \
        RD(4, RB) RD(5, RB) RD(6, RB) RD(7, RB)                                       \
        if (DO_PF) {                                                                  \
            P[0] = *(const h4*)(pp);                                                  \
            P[1] = *(const h4*)(pp + 8192);                                           \
            pp += sb;                                                                 \
        }                                                                             \
        MM(0, 7) MM(1, 6) MM(2, 5) MM(3, 4)                                           \
        MM(4, 3) MM(5, 2) MM(6, 1) MM(7, 0)                                           \
        h4 o0, o1;                                                                    \
        _Pragma("unroll")                                                             \
        for (int i = 0; i < 4; ++i) o0[i] = (_Float16)ftanh(acc0[i]);                 \
        *(h4*)(hbc + (WB) + wb0) = o0;                                                \
        _Pragma("unroll")                                                             \
        for (int i = 0; i < 4; ++i) o1[i] = (_Float16)ftanh(acc1[i]);                 \
        *(h4*)(hbc + (WB) + wb0 + 512) = o1;                                          \
        __builtin_amdgcn_sched_barrier(0);                                            \
        asm volatile("s_waitcnt lgkmcnt(0)" ::: "memory");                            \
        __builtin_amdgcn_s_barrier();                                                 \
        __builtin_amdgcn_sched_barrier(0);                                            \
    } while (0)

    for (int tp = 0; tp < 255; ++tp) {
        RNN_STEP(0, 8192, pA, 1);
        RNN_STEP(8192, 0, pB, 1);
    }
    RNN_STEP(0, 8192, pA, 0);

    {
        // step 511: read buf1, write hcat
        f32x4 acc0, acc1;
#pragma unroll
        for (int i = 0; i < 4; ++i) { acc0[i] = (float)pB[0][i]; acc1[i] = (float)pB[1][i]; }
        h8 bf[8];
#pragma unroll
        for (int kk = 0; kk < 8; ++kk)
            bf[kk] = *(const h8*)(hbc + 8192 + kk * 1024 + rb);
#pragma unroll
        for (int kk = 0; kk < 8; ++kk) {
            acc0 = __builtin_amdgcn_mfma_f32_16x16x32_f16(afrag[0][kk], bf[kk], acc0, 0, 0, 0);
            acc1 = __builtin_amdgcn_mfma_f32_16x16x32_f16(afrag[1][kk], bf[kk], acc1, 0, 0, 0);
        }
        f4 v0, v1;
#pragma unroll
        for (int i = 0; i < 4; ++i) { v0[i] = ftanh(acc0[i]); v1[i] = ftanh(acc1[i]); }
        float* hc = hcat + (size_t)(b0 + lj) * N2 + dirOff + j0 + lg * 4;
        *(f4*)hc = v0;
        *(f4*)(hc + 16) = v1;
    }
#undef RNN_STEP
#undef MM
#undef RD
}

// ---------------- head: 64 blocks x 4 batch-rows (R6-verified) ----------------
__global__ __launch_bounds__(256) void head_mlp(
    const float* __restrict__ hcat,
    const float* __restrict__ fc1w, const float* __restrict__ fc1b,
    const float* __restrict__ fc2w, const float* __restrict__ fc2b,
    const float* __restrict__ fsw, const float* __restrict__ fsb,
    float* __restrict__ out)
{
    __shared__ float hs[4 * 512];
    __shared__ float y1[4 * 512];
    __shared__ float y2[4 * 256];
    const int tid = threadIdx.x;
    const int b0 = blockIdx.x * 4;
    const int r = tid >> 6;
    const int lane = tid & 63;

#pragma unroll
    for (int c = 0; c < 2; ++c)
        ((f4*)hs)[c * 256 + tid] = ((const f4*)(hcat + (size_t)b0 * N2))[c * 256 + tid];
    __syncthreads();

    {
        const int j0 = lane * 8;
        f4 a0 = *(const f4*)(fc1b + j0);
        f4 a1 = *(const f4*)(fc1b + j0 + 4);
        for (int k = 0; k < 512; ++k) {
            float h = hs[r * 512 + k];
            f4 w0 = *(const f4*)(fc1w + (size_t)k * 512 + j0);
            f4 w1 = *(const f4*)(fc1w + (size_t)k * 512 + j0 + 4);
#pragma unroll
            for (int i = 0; i < 4; ++i) { a0[i] = fmaf(h, w0[i], a0[i]); a1[i] = fmaf(h, w1[i], a1[i]); }
        }
#pragma unroll
        for (int i = 0; i < 4; ++i) {
            y1[r * 512 + j0 + i]     = fmaxf(a0[i], 0.f);
            y1[r * 512 + j0 + 4 + i] = fmaxf(a1[i], 0.f);
        }
    }
    __syncthreads();

    {
        const int j2 = lane * 4;
        f4 a = *(const f4*)(fc2b + j2);
        for (int k = 0; k < 512; ++k) {
            float yv = y1[r * 512 + k];
            f4 w = *(const f4*)(fc2w + (size_t)k * 256 + j2);
#pragma unroll
            for (int i = 0; i < 4; ++i) a[i] = fmaf(yv, w[i], a[i]);
        }
#pragma unroll
        for (int i = 0; i < 4; ++i) y2[r * 256 + j2 + i] = fmaxf(a[i], 0.f);
    }
    __syncthreads();

    {
        float p = 0.f;
#pragma unroll
        for (int u = 0; u < 4; ++u)
            p = fmaf(y2[r * 256 + lane + u * 64], fsw[lane + u * 64], p);
#pragma unroll
        for (int off = 32; off > 0; off >>= 1) p += __shfl_down(p, off);
        if (lane == 0) out[b0 + r] = ftanh(p + fsb[0]);
    }
}

extern "C" void kernel_launch(void* const* d_in, const int* in_sizes, int n_in,
                              void* d_out, int out_size, void* d_ws, size_t ws_size,
                              hipStream_t stream)
{
    const float* x    = (const float*)d_in[0];
    const float* W1x  = (const float*)d_in[1];
    const float* W1h  = (const float*)d_in[2];
    const float* b1   = (const float*)d_in[3];
    const float* W2x  = (const float*)d_in[4];
    const float* W2h  = (const float*)d_in[5];
    const float* b2   = (const float*)d_in[6];
    const float* fc1w = (const float*)d_in[7];
    const float* fc1b = (const float*)d_in[8];
    const float* fc2w = (const float*)d_in[9];
    const float* fc2b = (const float*)d_in[10];
    const float* fsw  = (const float*)d_in[11];
    const float* fsb  = (const float*)d_in[12];

    char* ws = (char*)d_ws;
    size_t off = 0;
    _Float16* WTs  = (_Float16*)(ws + off); off += (size_t)N2 * KP * sizeof(_Float16);
    float* bcat    = (float*)(ws + off);    off += (size_t)N2 * sizeof(float);
    float* hcat    = (float*)(ws + off);    off += (size_t)BATCH * N2 * sizeof(float);
    _Float16* pre3 = (_Float16*)(ws + off); off += (size_t)SEQL * BATCH * N2 * sizeof(_Float16);
    if (off > ws_size) return;

    prep_kernel<<<(N2 * KP + 255) / 256, 256, 0, stream>>>(W1x, W2x, b1, b2, WTs, bcat);
    gemm_pre<<<2048, 512, 0, stream>>>(x, WTs, bcat, pre3);
    rnn_scan<<<(BATCH / 16) * 2, 512, 0, stream>>>(W1h, W2h, pre3, hcat);
    head_mlp<<<64, 256, 0, stream>>>(hcat, fc1w, fc1b, fc2w, fc2b, fsw, fsb, (float*)d_out);
}